// Round 6
// baseline (277.335 us; speedup 1.0000x reference)
//
#include <hip/hip_runtime.h>
#include <cstdint>
#include <cstddef>

// ---------------------------------------------------------------------------
// MultiHeadAttention: B=2 S=2048 D=1024 H=16 DK=64, causal, RoPE on q/k.
// cvt(fp32->bf16) -> fused QKV GEMM (64x128 tile, grid 1536, dbuf LDS)
// -> flash attention (paired q-tiles, lean softmax, XOR swizzle)
// -> O GEMM (64x128, dbuf) -> fp32 out.
// R5 post-mortem: inline-asm vmcnt pipelining regressed (VALU re-materialize,
// m141 failure mode) — reverted to __syncthreads dbuf; occupancy via retile.
// ---------------------------------------------------------------------------

typedef __bf16 bf16x8 __attribute__((ext_vector_type(8)));
typedef float floatx4 __attribute__((ext_vector_type(4)));

#define DI __device__ __forceinline__

DI unsigned short f2bf(float f) {
  union { float f; unsigned int u; } v; v.f = f;
  unsigned int r = v.u + 0x7fffu + ((v.u >> 16) & 1u);  // RNE
  return (unsigned short)(r >> 16);
}

DI unsigned short bfb(float f) {
  __bf16 h = (__bf16)f;
  union { __bf16 h; unsigned short u; } c; c.h = h;
  return c.u;
}

DI void async_ld16(const void* g, void* l) {
  __builtin_amdgcn_global_load_lds(
      (const __attribute__((address_space(1))) unsigned int*)g,
      (__attribute__((address_space(3))) unsigned int*)l, 16, 0, 0);
}

// ---------------------------------------------------------------------------
// One-shot fp32 -> bf16 convert of Q,K,V,Wq,Wk,Wv,Wo into contiguous ws.
// ---------------------------------------------------------------------------
__global__ void cvt_all(const float* __restrict__ Q, const float* __restrict__ K,
                        const float* __restrict__ V, const float* __restrict__ Wq,
                        const float* __restrict__ Wk, const float* __restrict__ Wv,
                        const float* __restrict__ Wo, unsigned short* __restrict__ dst) {
  int i = blockIdx.x * blockDim.x + threadIdx.x;  // 0..4194303
  const float* s;
  int off;
  if (i < 3145728) {
    if (i < 1048576) { s = Q; off = i; }
    else if (i < 2097152) { s = K; off = i - 1048576; }
    else { s = V; off = i - 2097152; }
  } else {
    int j = i - 3145728;
    int wsel = j >> 18;
    off = j & 262143;
    s = (wsel == 0) ? Wq : (wsel == 1) ? Wk : (wsel == 2) ? Wv : Wo;
  }
  float4 f = reinterpret_cast<const float4*>(s)[off];
  ushort4 o;
  o.x = f2bf(f.x); o.y = f2bf(f.y); o.z = f2bf(f.z); o.w = f2bf(f.w);
  reinterpret_cast<ushort4*>(dst)[i] = o;
}

// ---------------------------------------------------------------------------
// Fused QKV projection, 64x128 (MxN) tile, grid 1536 (3 proj x 64 yb x 8 xb)
// => ~5-6 blocks/CU for latency hiding. 4 waves in 2x2, each wave 32x64.
// Dbuf LDS staging (3 loads/thread/iter). id%8 == yb%8 -> the 8 xb-blocks
// sharing an X row-slice land on one XCD.
// proj==2 computes the transposed tile (A<->B swapped) for coalesced
// [B,H,DK,S] stores.
// ---------------------------------------------------------------------------
__global__ __launch_bounds__(256, 5)
void gemm_qkv(const unsigned short* __restrict__ Qb, const unsigned short* __restrict__ Kb,
              const unsigned short* __restrict__ Vb, const unsigned short* __restrict__ Wq,
              const unsigned short* __restrict__ Wk, const unsigned short* __restrict__ Wv,
              const float* __restrict__ bq, const float* __restrict__ bk,
              const float* __restrict__ bv, unsigned short* __restrict__ qh,
              unsigned short* __restrict__ kh, unsigned short* __restrict__ vtp,
              const float* __restrict__ cosT, const float* __restrict__ sinT) {
  __shared__ unsigned short As[2][64 * 32];
  __shared__ unsigned short Bs[2][128 * 32];

  const int id = blockIdx.x;
  const int xb = id / 192;         // 0..7 col-block
  const int rem = id - xb * 192;   // 0..191
  const int proj = rem >> 6;       // 0..2
  const int yb = rem & 63;         // 0..63; id%8 == yb%8 -> same XCD

  const unsigned short* X = (proj == 0) ? Qb : (proj == 1) ? Kb : Vb;
  const unsigned short* W = (proj == 0) ? Wq : (proj == 1) ? Wk : Wv;
  const float* bias = (proj == 0) ? bq : (proj == 1) ? bk : bv;
  unsigned short* outB = (proj == 0) ? qh : (proj == 1) ? kh : vtp;

  const int t = threadIdx.x;
  const int lane = t & 63;
  const int w = t >> 6;
  const int row0 = yb * 64;
  const int col0 = xb * 128;
  const int wm = (w >> 1) * 32;
  const int wn = (w & 1) * 64;
  const int fr = lane & 15;
  const int fk = (lane >> 4) * 8;
  const int rbase = (lane >> 4) * 4;

  floatx4 acc[2][4];
#pragma unroll
  for (int i = 0; i < 2; ++i)
#pragma unroll
    for (int j = 0; j < 4; ++j)
      acc[i][j] = (floatx4){0.f, 0.f, 0.f, 0.f};

  auto stage = [&](int k0, int buf) {
    {
      int c = t;
      int r = c >> 2, cc = c & 3;
      async_ld16(X + (size_t)(row0 + r) * 1024 + k0 + cc * 8, &As[buf][c * 8]);
    }
#pragma unroll
    for (int it = 0; it < 2; ++it) {
      int c = it * 256 + t;
      int r = c >> 2, cc = c & 3;
      async_ld16(W + (size_t)(col0 + r) * 1024 + k0 + cc * 8, &Bs[buf][c * 8]);
    }
  };

  stage(0, 0);
  __syncthreads();

  for (int kb = 0; kb < 32; ++kb) {
    const int cur = kb & 1;
    if (kb + 1 < 32) stage((kb + 1) * 32, cur ^ 1);

    bf16x8 af[2], bfr[4];
#pragma unroll
    for (int i = 0; i < 2; ++i)
      af[i] = *reinterpret_cast<const bf16x8*>(&As[cur][(wm + i * 16 + fr) * 32 + fk]);
#pragma unroll
    for (int j = 0; j < 4; ++j)
      bfr[j] = *reinterpret_cast<const bf16x8*>(&Bs[cur][(wn + j * 16 + fr) * 32 + fk]);
    if (proj == 2) {
#pragma unroll
      for (int i = 0; i < 2; ++i)
#pragma unroll
        for (int j = 0; j < 4; ++j)
          acc[i][j] = __builtin_amdgcn_mfma_f32_16x16x32_bf16(bfr[j], af[i], acc[i][j], 0, 0, 0);
    } else {
#pragma unroll
      for (int i = 0; i < 2; ++i)
#pragma unroll
        for (int j = 0; j < 4; ++j)
          acc[i][j] = __builtin_amdgcn_mfma_f32_16x16x32_bf16(af[i], bfr[j], acc[i][j], 0, 0, 0);
    }
    __syncthreads();
  }

  if (proj < 2) {
#pragma unroll
    for (int j = 0; j < 4; ++j) {
      const int col = col0 + wn + j * 16 + fr;
      const float bvv = bias[col];
#pragma unroll
      for (int i = 0; i < 2; ++i) {
#pragma unroll
        for (int r = 0; r < 4; ++r) {
          const int row = row0 + wm + i * 16 + rbase + r;
          float v = acc[i][j][r] + bvv;
          const int bb = row >> 11, sp = row & 2047, hh = col >> 6, dk = col & 63;
          float p = __shfl_xor(v, 1);
          const int i2 = (col & 63) >> 1;
          const float cv = cosT[sp * 32 + i2];
          const float sv = sinT[sp * 32 + i2];
          float res = ((col & 1) == 0) ? (v * cv - p * sv) : (p * sv + v * cv);
          if (proj == 0) res *= 0.125f;  // 1/sqrt(DK)
          outB[(((size_t)(bb * 16 + hh)) * 2048 + sp) * 64 + dk] = f2bf(res);
        }
      }
    }
  } else {
    // transposed tile: acc[i][j][r] = C[sp=row0+wm+i*16+fr][dkc=col0+wn+j*16+rbase+r]
#pragma unroll
    for (int j = 0; j < 4; ++j) {
#pragma unroll
      for (int r = 0; r < 4; ++r) {
        const int dkc = col0 + wn + j * 16 + rbase + r;
        const float bvv = bias[dkc];
        const int hh = dkc >> 6, dk = dkc & 63;
#pragma unroll
        for (int i = 0; i < 2; ++i) {
          const int spf = row0 + wm + i * 16 + fr;
          const int bb = spf >> 11, sp = spf & 2047;
          vtp[(((size_t)(bb * 16 + hh)) * 64 + dk) * 2048 + sp] = f2bf(acc[i][j][r] + bvv);
        }
      }
    }
  }
}

// ---------------------------------------------------------------------------
// Output projection: fp32 out = ao @ Wo^T + bo. 64x128 tile, grid 512,
// dbuf LDS staging (R4 form).
// ---------------------------------------------------------------------------
__global__ __launch_bounds__(256)
void gemm_out(const unsigned short* __restrict__ X, const unsigned short* __restrict__ W,
              const float* __restrict__ bias, float* __restrict__ outF) {
  __shared__ unsigned short As[2][64 * 32];
  __shared__ unsigned short Bs[2][128 * 32];

  const int id = blockIdx.x;
  const int xb = id >> 6;
  const int yb = id & 63;

  const int t = threadIdx.x;
  const int lane = t & 63;
  const int w = t >> 6;
  const int row0 = yb * 64;
  const int col0 = xb * 128;
  const int wm = (w >> 1) * 32;
  const int wn = (w & 1) * 64;
  const int fr = lane & 15;
  const int fk = (lane >> 4) * 8;
  const int rbase = (lane >> 4) * 4;

  floatx4 acc[2][4];
#pragma unroll
  for (int i = 0; i < 2; ++i)
#pragma unroll
    for (int j = 0; j < 4; ++j)
      acc[i][j] = (floatx4){0.f, 0.f, 0.f, 0.f};

  auto stage = [&](int k0, int buf) {
    {
      int c = t;
      int r = c >> 2, cc = c & 3;
      async_ld16(X + (size_t)(row0 + r) * 1024 + k0 + cc * 8, &As[buf][c * 8]);
    }
#pragma unroll
    for (int it = 0; it < 2; ++it) {
      int c = it * 256 + t;
      int r = c >> 2, cc = c & 3;
      async_ld16(W + (size_t)(col0 + r) * 1024 + k0 + cc * 8, &Bs[buf][c * 8]);
    }
  };

  stage(0, 0);
  __syncthreads();

  for (int kb = 0; kb < 32; ++kb) {
    const int cur = kb & 1;
    if (kb + 1 < 32) stage((kb + 1) * 32, cur ^ 1);

    bf16x8 af[2], bfr[4];
#pragma unroll
    for (int i = 0; i < 2; ++i)
      af[i] = *reinterpret_cast<const bf16x8*>(&As[cur][(wm + i * 16 + fr) * 32 + fk]);
#pragma unroll
    for (int j = 0; j < 4; ++j)
      bfr[j] = *reinterpret_cast<const bf16x8*>(&Bs[cur][(wn + j * 16 + fr) * 32 + fk]);
#pragma unroll
    for (int i = 0; i < 2; ++i)
#pragma unroll
      for (int j = 0; j < 4; ++j)
        acc[i][j] = __builtin_amdgcn_mfma_f32_16x16x32_bf16(af[i], bfr[j], acc[i][j], 0, 0, 0);
    __syncthreads();
  }

#pragma unroll
  for (int j = 0; j < 4; ++j) {
    const int col = col0 + wn + j * 16 + fr;
    const float bvv = bias[col];
#pragma unroll
    for (int i = 0; i < 2; ++i)
#pragma unroll
      for (int r = 0; r < 4; ++r) {
        const int row = row0 + wm + i * 16 + rbase + r;
        outF[(size_t)row * 1024 + col] = acc[i][j][r] + bvv;
      }
  }
}

// ---------------------------------------------------------------------------
// Flash attention, causal, paired q-tiles (qa, 31-qa), lean softmax,
// XOR-swizzled LDS, dbuf K/V staging (R4 form).
// ---------------------------------------------------------------------------
__global__ __launch_bounds__(256)
void flash_attn(const unsigned short* __restrict__ qh,
                const unsigned short* __restrict__ kh,
                const unsigned short* __restrict__ vt,
                unsigned short* __restrict__ out) {
  __shared__ unsigned short Ks[2][64 * 64];
  __shared__ unsigned short Vs[2][64 * 64];
  __shared__ unsigned short Ps[8][16 * 64];

  const int t = threadIdx.x, lane = t & 63, w = t >> 6;
  const int g = lane >> 4;
  const int fr = lane & 15;
  const int fk = g * 8;
  const int rbase = g * 4;
  const int id = blockIdx.x;
  const int qbA = id >> 5;
  const int bh = id & 31;
  const int qbB = 31 - qbA;
  const int qwA = qbA * 64 + w * 16;
  const int qwB = qbB * 64 + w * 16;

  const size_t baseQK = (size_t)bh * 2048 * 64;
  const size_t baseV = (size_t)bh * 64 * 2048;

  bf16x8 qfA[2], qfB[2];
  qfA[0] = *reinterpret_cast<const bf16x8*>(&qh[baseQK + (size_t)(qwA + fr) * 64 + fk]);
  qfA[1] = *reinterpret_cast<const bf16x8*>(&qh[baseQK + (size_t)(qwA + fr) * 64 + 32 + fk]);
  qfB[0] = *reinterpret_cast<const bf16x8*>(&qh[baseQK + (size_t)(qwB + fr) * 64 + fk]);
  qfB[1] = *reinterpret_cast<const bf16x8*>(&qh[baseQK + (size_t)(qwB + fr) * 64 + 32 + fk]);

  floatx4 oA[4], oB[4];
  float lA[4], lB[4];
#pragma unroll
  for (int i = 0; i < 4; ++i) {
    oA[i] = (floatx4){0.f, 0.f, 0.f, 0.f};
    oB[i] = (floatx4){0.f, 0.f, 0.f, 0.f};
    lA[i] = 0.f; lB[i] = 0.f;
  }

  auto stage = [&](int kb, int buf) {
    const int k0 = kb * 64;
#pragma unroll
    for (int it = 0; it < 2; ++it) {
      int c = it * 256 + t;
      int r = c >> 3, cg = (c & 7) ^ (r & 7);
      async_ld16(kh + baseQK + (size_t)(k0 + r) * 64 + cg * 8, &Ks[buf][c * 8]);
    }
#pragma unroll
    for (int it = 0; it < 2; ++it) {
      int c = it * 256 + t;
      int r = c >> 3, cg = (c & 7) ^ (r & 7);
      async_ld16(vt + baseV + (size_t)r * 2048 + k0 + cg * 8, &Vs[buf][c * 8]);
    }
  };

  const int nkb = qbB + 1;
  stage(0, 0);
  __syncthreads();

  for (int kb = 0; kb < nkb; ++kb) {
    const int cur = kb & 1;
    if (kb + 1 < nkb) stage(kb + 1, cur ^ 1);
    const int k0 = kb * 64;
    const bool aAct = (kb <= qbA);

    bf16x8 kf[4][2];
#pragma unroll
    for (int j = 0; j < 4; ++j)
#pragma unroll
      for (int kk = 0; kk < 2; ++kk)
        kf[j][kk] = *reinterpret_cast<const bf16x8*>(
            &Ks[cur][(j * 16 + fr) * 64 + ((((kk << 2) | g) ^ (fr & 7)) << 3)]);

    floatx4 sB[4], sA[4];
#pragma unroll
    for (int j = 0; j < 4; ++j) {
      sB[j] = (floatx4){0.f, 0.f, 0.f, 0.f};
      sA[j] = (floatx4){0.f, 0.f, 0.f, 0.f};
    }
#pragma unroll
    for (int j = 0; j < 4; ++j)
#pragma unroll
      for (int kk = 0; kk < 2; ++kk)
        sB[j] = __builtin_amdgcn_mfma_f32_16x16x32_bf16(qfB[kk], kf[j][kk], sB[j], 0, 0, 0);
    if (aAct) {
#pragma unroll
      for (int j = 0; j < 4; ++j)
#pragma unroll
        for (int kk = 0; kk < 2; ++kk)
          sA[j] = __builtin_amdgcn_mfma_f32_16x16x32_bf16(qfA[kk], kf[j][kk], sA[j], 0, 0, 0);
    }

    if (k0 + 63 > qwB) {
#pragma unroll
      for (int j = 0; j < 4; ++j)
#pragma unroll
        for (int r = 0; r < 4; ++r)
          if (k0 + j * 16 + fr > qwB + rbase + r) sB[j][r] = -1e30f;
    }
    if (aAct && k0 + 63 > qwA) {
#pragma unroll
      for (int j = 0; j < 4; ++j)
#pragma unroll
        for (int r = 0; r < 4; ++r)
          if (k0 + j * 16 + fr > qwA + rbase + r) sA[j][r] = -1e30f;
    }

#pragma unroll
    for (int j = 0; j < 4; ++j) {
      const int chb = (j * 16 + fr) >> 3;
      const int cin = fr & 7;
#pragma unroll
      for (int r = 0; r < 4; ++r) {
        const int row = rbase + r;
        float pB = __expf(sB[j][r]);
        lB[r] += pB;
        Ps[w][row * 64 + ((chb ^ (row & 7)) << 3) + cin] = bfb(pB);
      }
    }
    if (aAct) {
#pragma unroll
      for (int j = 0; j < 4; ++j) {
        const int chb = (j * 16 + fr) >> 3;
        const int cin = fr & 7;
#pragma unroll
        for (int r = 0; r < 4; ++r) {
          const int row = rbase + r;
          float pA = __expf(sA[j][r]);
          lA[r] += pA;
          Ps[w + 4][row * 64 + ((chb ^ (row & 7)) << 3) + cin] = bfb(pA);
        }
      }
    }

    bf16x8 vf[4][2], pB2[2], pA2[2];
#pragma unroll
    for (int id2 = 0; id2 < 4; ++id2)
#pragma unroll
      for (int kk = 0; kk < 2; ++kk)
        vf[id2][kk] = *reinterpret_cast<const bf16x8*>(
            &Vs[cur][(id2 * 16 + fr) * 64 + ((((kk << 2) | g) ^ (fr & 7)) << 3)]);
#pragma unroll
    for (int kk = 0; kk < 2; ++kk)
      pB2[kk] = *reinterpret_cast<const bf16x8*>(
          &Ps[w][fr * 64 + ((((kk << 2) | g) ^ (fr & 7)) << 3)]);
#pragma unroll
    for (int kk = 0; kk < 2; ++kk)
#pragma unroll
      for (int id2 = 0; id2 < 4; ++id2)
        oB[id2] = __builtin_amdgcn_mfma_f32_16x16x32_bf16(pB2[kk], vf[id2][kk], oB[id2], 0, 0, 0);
    if (aAct) {
#pragma unroll
      for (int kk = 0; kk < 2; ++kk)
        pA2[kk] = *reinterpret_cast<const bf16x8*>(
            &Ps[w + 4][fr * 64 + ((((kk << 2) | g) ^ (fr & 7)) << 3)]);
#pragma unroll
      for (int kk = 0; kk < 2; ++kk)
#pragma unroll
        for (int id2 = 0; id2 < 4; ++id2)
          oA[id2] = __builtin_amdgcn_mfma_f32_16x16x32_bf16(pA2[kk], vf[id2][kk], oA[id2], 0, 0, 0);
    }

    __syncthreads();
  }

#pragma unroll
  for (int r = 0; r < 4; ++r) {
#pragma unroll
    for (int d = 1; d < 16; d <<= 1) {
      lB[r] += __shfl_xor(lB[r], d);
      lA[r] += __shfl_xor(lA[r], d);
    }
  }

  const int bb = bh >> 4, hh = bh & 15;
#pragma unroll
  for (int id2 = 0; id2 < 4; ++id2)
#pragma unroll
    for (int r = 0; r < 4; ++r) {
      const int qrA = qwA + rbase + r;
      const int qrB = qwB + rbase + r;
      out[((size_t)(bb * 2048 + qrA)) * 1024 + hh * 64 + id2 * 16 + fr] = bfb(oA[id2][r] / lA[r]);
      out[((size_t)(bb * 2048 + qrB)) * 1024 + hh * 64 + id2 * 16 + fr] = bfb(oB[id2][r] / lB[r]);
    }
}

// ---------------------------------------------------------------------------
extern "C" void kernel_launch(void* const* d_in, const int* in_sizes, int n_in,
                              void* d_out, int out_size, void* d_ws, size_t ws_size,
                              hipStream_t stream) {
  const float* Q  = (const float*)d_in[0];
  const float* K  = (const float*)d_in[1];
  const float* V  = (const float*)d_in[2];
  const float* Wq = (const float*)d_in[4];
  const float* bq = (const float*)d_in[5];
  const float* Wk = (const float*)d_in[6];
  const float* bk = (const float*)d_in[7];
  const float* Wv = (const float*)d_in[8];
  const float* bv = (const float*)d_in[9];
  const float* Wo = (const float*)d_in[10];
  const float* bo = (const float*)d_in[11];
  const float* cosT = (const float*)d_in[12];
  const float* sinT = (const float*)d_in[13];

  char* ws = (char*)d_ws;
  const size_t MB = 1024 * 1024;
  unsigned short* Qb  = (unsigned short*)(ws + 0 * MB);
  unsigned short* Kb  = (unsigned short*)(ws + 8 * MB);
  unsigned short* Vb  = (unsigned short*)(ws + 16 * MB);
  unsigned short* Wqb = (unsigned short*)(ws + 24 * MB);
  unsigned short* Wkb = (unsigned short*)(ws + 26 * MB);
  unsigned short* Wvb = (unsigned short*)(ws + 28 * MB);
  unsigned short* Wob = (unsigned short*)(ws + 30 * MB);
  unsigned short* qh  = (unsigned short*)(ws + 32 * MB);
  unsigned short* khp = (unsigned short*)(ws + 40 * MB);
  unsigned short* vtp = (unsigned short*)(ws + 48 * MB);
  unsigned short* ao  = (unsigned short*)(ws + 56 * MB);

  cvt_all<<<16384, 256, 0, stream>>>(Q, K, V, Wq, Wk, Wv, Wo, (unsigned short*)ws);

  gemm_qkv<<<1536, 256, 0, stream>>>(Qb, Kb, Vb, Wqb, Wkb, Wvb, bq, bk, bv,
                                     qh, khp, vtp, cosT, sinT);
  flash_attn<<<512, 256, 0, stream>>>(qh, khp, vtp, ao);
  gemm_out<<<512, 256, 0, stream>>>(ao, Wob, bo, (float*)d_out);
}

// Round 7
// 248.967 us; speedup vs baseline: 1.1139x; 1.1139x over previous
//
#include <hip/hip_runtime.h>
#include <cstdint>
#include <cstddef>

// ---------------------------------------------------------------------------
// MultiHeadAttention: B=2 S=2048 D=1024 H=16 DK=64, causal, RoPE on q/k.
// This round: VGPR-mediated LDS staging (global->VGPR early, ds_write after
// compute) so the compiler's vmcnt wait lands AFTER the MFMA block and the
// __syncthreads drain is free. One barrier/iter. R6's retile reverted
// (qkv back to 128x128 / grid 768 — best observed config).
// ---------------------------------------------------------------------------

typedef __bf16 bf16x8 __attribute__((ext_vector_type(8)));
typedef float floatx4 __attribute__((ext_vector_type(4)));

#define DI __device__ __forceinline__

DI unsigned short f2bf(float f) {
  union { float f; unsigned int u; } v; v.f = f;
  unsigned int r = v.u + 0x7fffu + ((v.u >> 16) & 1u);  // RNE
  return (unsigned short)(r >> 16);
}

DI unsigned short bfb(float f) {
  __bf16 h = (__bf16)f;
  union { __bf16 h; unsigned short u; } c; c.h = h;
  return c.u;
}

// ---------------------------------------------------------------------------
// One-shot fp32 -> bf16 convert of Q,K,V,Wq,Wk,Wv,Wo into contiguous ws.
// ---------------------------------------------------------------------------
__global__ void cvt_all(const float* __restrict__ Q, const float* __restrict__ K,
                        const float* __restrict__ V, const float* __restrict__ Wq,
                        const float* __restrict__ Wk, const float* __restrict__ Wv,
                        const float* __restrict__ Wo, unsigned short* __restrict__ dst) {
  int i = blockIdx.x * blockDim.x + threadIdx.x;  // 0..4194303
  const float* s;
  int off;
  if (i < 3145728) {
    if (i < 1048576) { s = Q; off = i; }
    else if (i < 2097152) { s = K; off = i - 1048576; }
    else { s = V; off = i - 2097152; }
  } else {
    int j = i - 3145728;
    int wsel = j >> 18;
    off = j & 262143;
    s = (wsel == 0) ? Wq : (wsel == 1) ? Wk : (wsel == 2) ? Wv : Wo;
  }
  float4 f = reinterpret_cast<const float4*>(s)[off];
  ushort4 o;
  o.x = f2bf(f.x); o.y = f2bf(f.y); o.z = f2bf(f.z); o.w = f2bf(f.w);
  reinterpret_cast<ushort4*>(dst)[i] = o;
}

// ---------------------------------------------------------------------------
// Fused QKV projection, 128x128 tile, grid 768 (xb*96 + proj*32 + yb;
// id%8==yb%8 -> XCD sharing). VGPR-mediated dbuf staging, 1 barrier/iter.
// proj==2 computes the transposed tile (A<->B swapped) for coalesced
// [B,H,DK,S] stores.
// ---------------------------------------------------------------------------
__global__ __launch_bounds__(256)
void gemm_qkv(const unsigned short* __restrict__ Qb, const unsigned short* __restrict__ Kb,
              const unsigned short* __restrict__ Vb, const unsigned short* __restrict__ Wq,
              const unsigned short* __restrict__ Wk, const unsigned short* __restrict__ Wv,
              const float* __restrict__ bq, const float* __restrict__ bk,
              const float* __restrict__ bv, unsigned short* __restrict__ qh,
              unsigned short* __restrict__ kh, unsigned short* __restrict__ vtp,
              const float* __restrict__ cosT, const float* __restrict__ sinT) {
  __shared__ unsigned short As[2][128 * 32];
  __shared__ unsigned short Bs[2][128 * 32];

  const int id = blockIdx.x;
  const int xb = id / 96;
  const int rem = id - xb * 96;
  const int proj = rem >> 5;
  const int yb = rem & 31;

  const unsigned short* X = (proj == 0) ? Qb : (proj == 1) ? Kb : Vb;
  const unsigned short* W = (proj == 0) ? Wq : (proj == 1) ? Wk : Wv;
  const float* bias = (proj == 0) ? bq : (proj == 1) ? bk : bv;
  unsigned short* outB = (proj == 0) ? qh : (proj == 1) ? kh : vtp;

  const int t = threadIdx.x;
  const int lane = t & 63;
  const int w = t >> 6;
  const int row0 = yb * 128;
  const int col0 = xb * 128;
  const int wm = (w >> 1) * 64;
  const int wn = (w & 1) * 64;
  const int fr = lane & 15;
  const int fk = (lane >> 4) * 8;
  const int rbase = (lane >> 4) * 4;

  // per-thread staging addresses (2 A chunks + 2 B chunks of 16B)
  const int c0 = t, c1 = t + 256;
  const unsigned short* gA0 = X + (size_t)(row0 + (c0 >> 2)) * 1024 + (c0 & 3) * 8;
  const unsigned short* gA1 = X + (size_t)(row0 + (c1 >> 2)) * 1024 + (c1 & 3) * 8;
  const unsigned short* gB0 = W + (size_t)(col0 + (c0 >> 2)) * 1024 + (c0 & 3) * 8;
  const unsigned short* gB1 = W + (size_t)(col0 + (c1 >> 2)) * 1024 + (c1 & 3) * 8;

  floatx4 acc[4][4];
#pragma unroll
  for (int i = 0; i < 4; ++i)
#pragma unroll
    for (int j = 0; j < 4; ++j)
      acc[i][j] = (floatx4){0.f, 0.f, 0.f, 0.f};

  uint4 ra0, ra1, rb0, rb1;
  auto gload = [&](int k0) {
    ra0 = *reinterpret_cast<const uint4*>(gA0 + k0);
    ra1 = *reinterpret_cast<const uint4*>(gA1 + k0);
    rb0 = *reinterpret_cast<const uint4*>(gB0 + k0);
    rb1 = *reinterpret_cast<const uint4*>(gB1 + k0);
  };
  auto swrite = [&](int buf) {
    *reinterpret_cast<uint4*>(&As[buf][c0 * 8]) = ra0;
    *reinterpret_cast<uint4*>(&As[buf][c1 * 8]) = ra1;
    *reinterpret_cast<uint4*>(&Bs[buf][c0 * 8]) = rb0;
    *reinterpret_cast<uint4*>(&Bs[buf][c1 * 8]) = rb1;
  };

  gload(0);
  swrite(0);
  __syncthreads();

  for (int kb = 0; kb < 32; ++kb) {
    const int cur = kb & 1;
    if (kb + 1 < 32) gload((kb + 1) * 32);  // loads fly during compute

    bf16x8 af[4], bfr[4];
#pragma unroll
    for (int i = 0; i < 4; ++i)
      af[i] = *reinterpret_cast<const bf16x8*>(&As[cur][(wm + i * 16 + fr) * 32 + fk]);
#pragma unroll
    for (int j = 0; j < 4; ++j)
      bfr[j] = *reinterpret_cast<const bf16x8*>(&Bs[cur][(wn + j * 16 + fr) * 32 + fk]);
    if (proj == 2) {
#pragma unroll
      for (int i = 0; i < 4; ++i)
#pragma unroll
        for (int j = 0; j < 4; ++j)
          acc[i][j] = __builtin_amdgcn_mfma_f32_16x16x32_bf16(bfr[j], af[i], acc[i][j], 0, 0, 0);
    } else {
#pragma unroll
      for (int i = 0; i < 4; ++i)
#pragma unroll
        for (int j = 0; j < 4; ++j)
          acc[i][j] = __builtin_amdgcn_mfma_f32_16x16x32_bf16(af[i], bfr[j], acc[i][j], 0, 0, 0);
    }

    if (kb + 1 < 32) swrite(cur ^ 1);  // vmcnt wait lands here, after MFMAs
    __syncthreads();
  }

  if (proj < 2) {
#pragma unroll
    for (int j = 0; j < 4; ++j) {
      const int col = col0 + wn + j * 16 + fr;
      const float bvv = bias[col];
#pragma unroll
      for (int i = 0; i < 4; ++i) {
#pragma unroll
        for (int r = 0; r < 4; ++r) {
          const int row = row0 + wm + i * 16 + rbase + r;
          float v = acc[i][j][r] + bvv;
          const int bb = row >> 11, sp = row & 2047, hh = col >> 6, dk = col & 63;
          float p = __shfl_xor(v, 1);
          const int i2 = (col & 63) >> 1;
          const float cv = cosT[sp * 32 + i2];
          const float sv = sinT[sp * 32 + i2];
          float res = ((col & 1) == 0) ? (v * cv - p * sv) : (p * sv + v * cv);
          if (proj == 0) res *= 0.125f;  // 1/sqrt(DK)
          outB[(((size_t)(bb * 16 + hh)) * 2048 + sp) * 64 + dk] = f2bf(res);
        }
      }
    }
  } else {
    // transposed tile: acc[i][j][r] = C[sp=row0+wm+i*16+fr][dkc=col0+wn+j*16+rbase+r]
#pragma unroll
    for (int j = 0; j < 4; ++j) {
#pragma unroll
      for (int r = 0; r < 4; ++r) {
        const int dkc = col0 + wn + j * 16 + rbase + r;
        const float bvv = bias[dkc];
        const int hh = dkc >> 6, dk = dkc & 63;
#pragma unroll
        for (int i = 0; i < 4; ++i) {
          const int spf = row0 + wm + i * 16 + fr;
          const int bb = spf >> 11, sp = spf & 2047;
          vtp[(((size_t)(bb * 16 + hh)) * 64 + dk) * 2048 + sp] = f2bf(acc[i][j][r] + bvv);
        }
      }
    }
  }
}

// ---------------------------------------------------------------------------
// Output projection: fp32 out = ao @ Wo^T + bo. 64x128 tile, grid 512,
// VGPR-mediated dbuf staging.
// ---------------------------------------------------------------------------
__global__ __launch_bounds__(256)
void gemm_out(const unsigned short* __restrict__ X, const unsigned short* __restrict__ W,
              const float* __restrict__ bias, float* __restrict__ outF) {
  __shared__ unsigned short As[2][64 * 32];
  __shared__ unsigned short Bs[2][128 * 32];

  const int id = blockIdx.x;
  const int xb = id >> 6;
  const int yb = id & 63;

  const int t = threadIdx.x;
  const int lane = t & 63;
  const int w = t >> 6;
  const int row0 = yb * 64;
  const int col0 = xb * 128;
  const int wm = (w >> 1) * 32;
  const int wn = (w & 1) * 64;
  const int fr = lane & 15;
  const int fk = (lane >> 4) * 8;
  const int rbase = (lane >> 4) * 4;

  const int c0 = t, c1 = t + 256;
  const unsigned short* gA0 = X + (size_t)(row0 + (c0 >> 2)) * 1024 + (c0 & 3) * 8;
  const unsigned short* gB0 = W + (size_t)(col0 + (c0 >> 2)) * 1024 + (c0 & 3) * 8;
  const unsigned short* gB1 = W + (size_t)(col0 + (c1 >> 2)) * 1024 + (c1 & 3) * 8;

  floatx4 acc[2][4];
#pragma unroll
  for (int i = 0; i < 2; ++i)
#pragma unroll
    for (int j = 0; j < 4; ++j)
      acc[i][j] = (floatx4){0.f, 0.f, 0.f, 0.f};

  uint4 ra0, rb0, rb1;
  auto gload = [&](int k0) {
    ra0 = *reinterpret_cast<const uint4*>(gA0 + k0);
    rb0 = *reinterpret_cast<const uint4*>(gB0 + k0);
    rb1 = *reinterpret_cast<const uint4*>(gB1 + k0);
  };
  auto swrite = [&](int buf) {
    *reinterpret_cast<uint4*>(&As[buf][c0 * 8]) = ra0;
    *reinterpret_cast<uint4*>(&Bs[buf][c0 * 8]) = rb0;
    *reinterpret_cast<uint4*>(&Bs[buf][c1 * 8]) = rb1;
  };

  gload(0);
  swrite(0);
  __syncthreads();

  for (int kb = 0; kb < 32; ++kb) {
    const int cur = kb & 1;
    if (kb + 1 < 32) gload((kb + 1) * 32);

    bf16x8 af[2], bfr[4];
#pragma unroll
    for (int i = 0; i < 2; ++i)
      af[i] = *reinterpret_cast<const bf16x8*>(&As[cur][(wm + i * 16 + fr) * 32 + fk]);
#pragma unroll
    for (int j = 0; j < 4; ++j)
      bfr[j] = *reinterpret_cast<const bf16x8*>(&Bs[cur][(wn + j * 16 + fr) * 32 + fk]);
#pragma unroll
    for (int i = 0; i < 2; ++i)
#pragma unroll
      for (int j = 0; j < 4; ++j)
        acc[i][j] = __builtin_amdgcn_mfma_f32_16x16x32_bf16(af[i], bfr[j], acc[i][j], 0, 0, 0);

    if (kb + 1 < 32) swrite(cur ^ 1);
    __syncthreads();
  }

#pragma unroll
  for (int j = 0; j < 4; ++j) {
    const int col = col0 + wn + j * 16 + fr;
    const float bvv = bias[col];
#pragma unroll
    for (int i = 0; i < 2; ++i)
#pragma unroll
      for (int r = 0; r < 4; ++r) {
        const int row = row0 + wm + i * 16 + rbase + r;
        outF[(size_t)row * 1024 + col] = acc[i][j][r] + bvv;
      }
  }
}

// ---------------------------------------------------------------------------
// Flash attention, causal, paired q-tiles (qa, 31-qa), lean softmax,
// XOR-swizzled LDS (swizzle now applied on the ds_write address; global
// reads straight). VGPR-mediated dbuf K/V staging, 1 barrier/iter.
// ---------------------------------------------------------------------------
__global__ __launch_bounds__(256)
void flash_attn(const unsigned short* __restrict__ qh,
                const unsigned short* __restrict__ kh,
                const unsigned short* __restrict__ vt,
                unsigned short* __restrict__ out) {
  __shared__ unsigned short Ks[2][64 * 64];
  __shared__ unsigned short Vs[2][64 * 64];
  __shared__ unsigned short Ps[8][16 * 64];

  const int t = threadIdx.x, lane = t & 63, w = t >> 6;
  const int g = lane >> 4;
  const int fr = lane & 15;
  const int fk = g * 8;
  const int rbase = g * 4;
  const int id = blockIdx.x;
  const int qbA = id >> 5;
  const int bh = id & 31;
  const int qbB = 31 - qbA;
  const int qwA = qbA * 64 + w * 16;
  const int qwB = qbB * 64 + w * 16;

  const size_t baseQK = (size_t)bh * 2048 * 64;
  const size_t baseV = (size_t)bh * 64 * 2048;

  bf16x8 qfA[2], qfB[2];
  qfA[0] = *reinterpret_cast<const bf16x8*>(&qh[baseQK + (size_t)(qwA + fr) * 64 + fk]);
  qfA[1] = *reinterpret_cast<const bf16x8*>(&qh[baseQK + (size_t)(qwA + fr) * 64 + 32 + fk]);
  qfB[0] = *reinterpret_cast<const bf16x8*>(&qh[baseQK + (size_t)(qwB + fr) * 64 + fk]);
  qfB[1] = *reinterpret_cast<const bf16x8*>(&qh[baseQK + (size_t)(qwB + fr) * 64 + 32 + fk]);

  floatx4 oA[4], oB[4];
  float lA[4], lB[4];
#pragma unroll
  for (int i = 0; i < 4; ++i) {
    oA[i] = (floatx4){0.f, 0.f, 0.f, 0.f};
    oB[i] = (floatx4){0.f, 0.f, 0.f, 0.f};
    lA[i] = 0.f; lB[i] = 0.f;
  }

  // staging geometry: chunk c in 0..511 (2/thread per array), row r=c>>3,
  // straight global chunk cc=c&7, LDS slot r*8 + (cc ^ (r&7)).
  const int sc0 = t, sc1 = t + 256;
  const int r0 = sc0 >> 3, cc0 = sc0 & 7, d0 = (r0 * 8 + (cc0 ^ (r0 & 7))) * 8;
  const int r1 = sc1 >> 3, cc1 = sc1 & 7, d1 = (r1 * 8 + (cc1 ^ (r1 & 7))) * 8;

  uint4 rk0, rk1, rv0, rv1;
  auto gload = [&](int kb) {
    const int k0 = kb * 64;
    rk0 = *reinterpret_cast<const uint4*>(kh + baseQK + (size_t)(k0 + r0) * 64 + cc0 * 8);
    rk1 = *reinterpret_cast<const uint4*>(kh + baseQK + (size_t)(k0 + r1) * 64 + cc1 * 8);
    rv0 = *reinterpret_cast<const uint4*>(vt + baseV + (size_t)r0 * 2048 + k0 + cc0 * 8);
    rv1 = *reinterpret_cast<const uint4*>(vt + baseV + (size_t)r1 * 2048 + k0 + cc1 * 8);
  };
  auto swrite = [&](int buf) {
    *reinterpret_cast<uint4*>(&Ks[buf][d0]) = rk0;
    *reinterpret_cast<uint4*>(&Ks[buf][d1]) = rk1;
    *reinterpret_cast<uint4*>(&Vs[buf][d0]) = rv0;
    *reinterpret_cast<uint4*>(&Vs[buf][d1]) = rv1;
  };

  const int nkb = qbB + 1;
  gload(0);
  swrite(0);
  __syncthreads();

  for (int kb = 0; kb < nkb; ++kb) {
    const int cur = kb & 1;
    if (kb + 1 < nkb) gload(kb + 1);
    const int k0 = kb * 64;
    const bool aAct = (kb <= qbA);

    bf16x8 kf[4][2];
#pragma unroll
    for (int j = 0; j < 4; ++j)
#pragma unroll
      for (int kk = 0; kk < 2; ++kk)
        kf[j][kk] = *reinterpret_cast<const bf16x8*>(
            &Ks[cur][(j * 16 + fr) * 64 + ((((kk << 2) | g) ^ (fr & 7)) << 3)]);

    floatx4 sB[4], sA[4];
#pragma unroll
    for (int j = 0; j < 4; ++j) {
      sB[j] = (floatx4){0.f, 0.f, 0.f, 0.f};
      sA[j] = (floatx4){0.f, 0.f, 0.f, 0.f};
    }
#pragma unroll
    for (int j = 0; j < 4; ++j)
#pragma unroll
      for (int kk = 0; kk < 2; ++kk)
        sB[j] = __builtin_amdgcn_mfma_f32_16x16x32_bf16(qfB[kk], kf[j][kk], sB[j], 0, 0, 0);
    if (aAct) {
#pragma unroll
      for (int j = 0; j < 4; ++j)
#pragma unroll
        for (int kk = 0; kk < 2; ++kk)
          sA[j] = __builtin_amdgcn_mfma_f32_16x16x32_bf16(qfA[kk], kf[j][kk], sA[j], 0, 0, 0);
    }

    if (k0 + 63 > qwB) {
#pragma unroll
      for (int j = 0; j < 4; ++j)
#pragma unroll
        for (int r = 0; r < 4; ++r)
          if (k0 + j * 16 + fr > qwB + rbase + r) sB[j][r] = -1e30f;
    }
    if (aAct && k0 + 63 > qwA) {
#pragma unroll
      for (int j = 0; j < 4; ++j)
#pragma unroll
        for (int r = 0; r < 4; ++r)
          if (k0 + j * 16 + fr > qwA + rbase + r) sA[j][r] = -1e30f;
    }

#pragma unroll
    for (int j = 0; j < 4; ++j) {
      const int chb = (j * 16 + fr) >> 3;
      const int cin = fr & 7;
#pragma unroll
      for (int r = 0; r < 4; ++r) {
        const int row = rbase + r;
        float pB = __expf(sB[j][r]);
        lB[r] += pB;
        Ps[w][row * 64 + ((chb ^ (row & 7)) << 3) + cin] = bfb(pB);
      }
    }
    if (aAct) {
#pragma unroll
      for (int j = 0; j < 4; ++j) {
        const int chb = (j * 16 + fr) >> 3;
        const int cin = fr & 7;
#pragma unroll
        for (int r = 0; r < 4; ++r) {
          const int row = rbase + r;
          float pA = __expf(sA[j][r]);
          lA[r] += pA;
          Ps[w + 4][row * 64 + ((chb ^ (row & 7)) << 3) + cin] = bfb(pA);
        }
      }
    }

    bf16x8 vf[4][2], pB2[2], pA2[2];
#pragma unroll
    for (int id2 = 0; id2 < 4; ++id2)
#pragma unroll
      for (int kk = 0; kk < 2; ++kk)
        vf[id2][kk] = *reinterpret_cast<const bf16x8*>(
            &Vs[cur][(id2 * 16 + fr) * 64 + ((((kk << 2) | g) ^ (fr & 7)) << 3)]);
#pragma unroll
    for (int kk = 0; kk < 2; ++kk)
      pB2[kk] = *reinterpret_cast<const bf16x8*>(
          &Ps[w][fr * 64 + ((((kk << 2) | g) ^ (fr & 7)) << 3)]);
#pragma unroll
    for (int kk = 0; kk < 2; ++kk)
#pragma unroll
      for (int id2 = 0; id2 < 4; ++id2)
        oB[id2] = __builtin_amdgcn_mfma_f32_16x16x32_bf16(pB2[kk], vf[id2][kk], oB[id2], 0, 0, 0);
    if (aAct) {
#pragma unroll
      for (int kk = 0; kk < 2; ++kk)
        pA2[kk] = *reinterpret_cast<const bf16x8*>(
            &Ps[w + 4][fr * 64 + ((((kk << 2) | g) ^ (fr & 7)) << 3)]);
#pragma unroll
      for (int kk = 0; kk < 2; ++kk)
#pragma unroll
        for (int id2 = 0; id2 < 4; ++id2)
          oA[id2] = __builtin_amdgcn_mfma_f32_16x16x32_bf16(pA2[kk], vf[id2][kk], oA[id2], 0, 0, 0);
    }

    if (kb + 1 < nkb) swrite(cur ^ 1);  // vmcnt wait lands here
    __syncthreads();
  }

#pragma unroll
  for (int r = 0; r < 4; ++r) {
#pragma unroll
    for (int d = 1; d < 16; d <<= 1) {
      lB[r] += __shfl_xor(lB[r], d);
      lA[r] += __shfl_xor(lA[r], d);
    }
  }

  const int bb = bh >> 4, hh = bh & 15;
#pragma unroll
  for (int id2 = 0; id2 < 4; ++id2)
#pragma unroll
    for (int r = 0; r < 4; ++r) {
      const int qrA = qwA + rbase + r;
      const int qrB = qwB + rbase + r;
      out[((size_t)(bb * 2048 + qrA)) * 1024 + hh * 64 + id2 * 16 + fr] = bfb(oA[id2][r] / lA[r]);
      out[((size_t)(bb * 2048 + qrB)) * 1024 + hh * 64 + id2 * 16 + fr] = bfb(oB[id2][r] / lB[r]);
    }
}

// ---------------------------------------------------------------------------
extern "C" void kernel_launch(void* const* d_in, const int* in_sizes, int n_in,
                              void* d_out, int out_size, void* d_ws, size_t ws_size,
                              hipStream_t stream) {
  const float* Q  = (const float*)d_in[0];
  const float* K  = (const float*)d_in[1];
  const float* V  = (const float*)d_in[2];
  const float* Wq = (const float*)d_in[4];
  const float* bq = (const float*)d_in[5];
  const float* Wk = (const float*)d_in[6];
  const float* bk = (const float*)d_in[7];
  const float* Wv = (const float*)d_in[8];
  const float* bv = (const float*)d_in[9];
  const float* Wo = (const float*)d_in[10];
  const float* bo = (const float*)d_in[11];
  const float* cosT = (const float*)d_in[12];
  const float* sinT = (const float*)d_in[13];

  char* ws = (char*)d_ws;
  const size_t MB = 1024 * 1024;
  unsigned short* Qb  = (unsigned short*)(ws + 0 * MB);
  unsigned short* Kb  = (unsigned short*)(ws + 8 * MB);
  unsigned short* Vb  = (unsigned short*)(ws + 16 * MB);
  unsigned short* Wqb = (unsigned short*)(ws + 24 * MB);
  unsigned short* Wkb = (unsigned short*)(ws + 26 * MB);
  unsigned short* Wvb = (unsigned short*)(ws + 28 * MB);
  unsigned short* Wob = (unsigned short*)(ws + 30 * MB);
  unsigned short* qh  = (unsigned short*)(ws + 32 * MB);
  unsigned short* khp = (unsigned short*)(ws + 40 * MB);
  unsigned short* vtp = (unsigned short*)(ws + 48 * MB);
  unsigned short* ao  = (unsigned short*)(ws + 56 * MB);

  cvt_all<<<16384, 256, 0, stream>>>(Q, K, V, Wq, Wk, Wv, Wo, (unsigned short*)ws);

  gemm_qkv<<<768, 256, 0, stream>>>(Qb, Kb, Vb, Wqb, Wkb, Wvb, bq, bk, bv,
                                    qh, khp, vtp, cosT, sinT);
  flash_attn<<<512, 256, 0, stream>>>(qh, khp, vtp, ao);
  gemm_out<<<512, 256, 0, stream>>>(ao, Wob, bo, (float*)d_out);
}